// Round 10
// baseline (65.115 us; speedup 1.0000x reference)
//
#include <hip/hip_runtime.h>

#define NPART 4096
#define DIM 32
#define LOG2E 1.44269504088896340736f

typedef _Float16 f16x8 __attribute__((ext_vector_type(8)));
typedef _Float16 f16x4 __attribute__((ext_vector_type(4)));
typedef float f32x4 __attribute__((ext_vector_type(4)));

// ---------------------------------------------------------------------------
// Single-pass kernel (R8 3-pass body, known-good). MEASUREMENT config: the
// j-grid is replicated REP=4x (blockIdx.y & 7 selects the real j-chunk) and
// each block scales its contribution by 1/REP — bit-exact output, 4x runtime,
// so the kernel becomes visible in rocprof top-5 over the harness fills.
#define REP 4
__global__ __launch_bounds__(256, 4) void svgd_onepass_kernel(
    const float* __restrict__ X, const float* __restrict__ ls,
    float* __restrict__ out) {
  // LDS carve (26624 B). sT overlays sHi+sLo (valid after final barrier).
  __shared__ __align__(16) unsigned char smem[26624];
  _Float16* sHi = (_Float16*)smem;             // [128][32] frag-order hi
  _Float16* sLo = (_Float16*)(smem + 8192);    // [128][32] frag-order lo
  _Float16* sXT = (_Float16*)(smem + 16384);   // [32][136] transpose (padded)
  float* sM2 = (float*)(smem + 25088);         // [2][128] norm partials
  float* sS = (float*)(smem + 26112);          // [4][32]
  float* sT = (float*)smem;                    // overlay [4][32][32]

  const int tid = threadIdx.x;
  const int lane = tid & 63;
  const int g = lane >> 4;    // 0..3
  const int li = lane & 15;   // 0..15
  const int wave = tid >> 6;  // 0..3
  const int i0 = blockIdx.x * 32;
  const int jb0 = (blockIdx.y & 7) * 512;

  const float lsv = ls[0];
  const float inv = 1.f / (lsv * lsv);
  const float si2 = LOG2E * inv;
  const float hm = 0.5f * si2;

  const float4* X4 = (const float4*)X;

  // ---- i-tile fragments + norms, in registers (verified R3 lane mapping) --
  f16x8 bh0, bl0, bh1, bl1;
  float mi0, mi1;
  {
    const int r0 = i0 + li, r1 = i0 + 16 + li;
    float4 a0 = X4[(size_t)r0 * 8 + g], b0 = X4[(size_t)r0 * 8 + 4 + g];
    float4 a1 = X4[(size_t)r1 * 8 + g], b1 = X4[(size_t)r1 * 8 + 4 + g];
    float t0[8] = {a0.x, a0.y, a0.z, a0.w, b0.x, b0.y, b0.z, b0.w};
    float t1[8] = {a1.x, a1.y, a1.z, a1.w, b1.x, b1.y, b1.z, b1.w};
    float n0 = 0.f, n1 = 0.f;
#pragma unroll
    for (int e = 0; e < 8; ++e) {
      n0 = fmaf(t0[e], t0[e], n0);
      n1 = fmaf(t1[e], t1[e], n1);
      _Float16 h0 = (_Float16)t0[e];
      _Float16 h1 = (_Float16)t1[e];
      bh0[e] = h0; bl0[e] = (_Float16)(t0[e] - (float)h0);
      bh1[e] = h1; bl1[e] = (_Float16)(t1[e] - (float)h1);
    }
    n0 += __shfl_xor(n0, 16, 64);
    n0 += __shfl_xor(n0, 32, 64);
    n1 += __shfl_xor(n1, 16, 64);
    n1 += __shfl_xor(n1, 32, 64);
    mi0 = n0 * hm;
    mi1 = n1 * hm;
  }

  f32x4 c2a0 = {0.f, 0.f, 0.f, 0.f}, c2b0 = {0.f, 0.f, 0.f, 0.f};
  f32x4 c2a1 = {0.f, 0.f, 0.f, 0.f}, c2b1 = {0.f, 0.f, 0.f, 0.f};
  float Sp0 = 0.f, Sp1 = 0.f;

  // ---- 4 stages of 128 j-rows: convert to LDS, then 2 COMP iters/wave ----
#pragma unroll
  for (int s = 0; s < 4; ++s) {
    __syncthreads();  // prior-stage consumers done
    {
      const int r = tid >> 1, sub = tid & 1;
      const int row = jb0 + s * 128 + r;
      const float4* src = X4 + (size_t)row * 8 + sub * 4;
      float4 va = src[0], vb = src[1], vc = src[2], vd = src[3];
      float tv[16] = {va.x, va.y, va.z, va.w, vb.x, vb.y, vb.z, vb.w,
                      vc.x, vc.y, vc.z, vc.w, vd.x, vd.y, vd.z, vd.w};
      _Float16 h[16], l[16];
      float nrm = 0.f;
#pragma unroll
      for (int e = 0; e < 16; ++e) {
        nrm = fmaf(tv[e], tv[e], nrm);
        _Float16 hh = (_Float16)tv[e];
        h[e] = hh;
        l[e] = (_Float16)(tv[e] - (float)hh);
      }
      sM2[sub * 128 + r] = nrm * hm;
#pragma unroll
      for (int gq = 0; gq < 4; ++gq) {
        f16x4 ph, pl;
#pragma unroll
        for (int e = 0; e < 4; ++e) { ph[e] = h[4 * gq + e]; pl[e] = l[4 * gq + e]; }
        *(f16x4*)(sHi + r * 32 + gq * 8 + sub * 4) = ph;
        *(f16x4*)(sLo + r * 32 + gq * 8 + sub * 4) = pl;
      }
#pragma unroll
      for (int e = 0; e < 16; ++e) sXT[(16 * sub + e) * 136 + r] = h[e];
    }
    __syncthreads();

#pragma unroll
    for (int it = 0; it < 2; ++it) {
      const int jloc = wave * 32 + it * 16;
      f16x8 Ah = *(const f16x8*)(sHi + (jloc + li) * 32 + g * 8);
      f16x8 Al = *(const f16x8*)(sLo + (jloc + li) * 32 + g * 8);
      f16x4 Ba = *(const f16x4*)(sXT + li * 136 + jloc + 4 * g);
      f16x4 Bb = *(const f16x4*)(sXT + (16 + li) * 136 + jloc + 4 * g);
      f32x4 Mja = *(const f32x4*)(sM2 + jloc + 4 * g);
      f32x4 Mjb = *(const f32x4*)(sM2 + 128 + jloc + 4 * g);

      f32x4 c10 = {0.f, 0.f, 0.f, 0.f}, c11 = {0.f, 0.f, 0.f, 0.f};
      c10 = __builtin_amdgcn_mfma_f32_16x16x32_f16(Ah, bh0, c10, 0, 0, 0);
      c11 = __builtin_amdgcn_mfma_f32_16x16x32_f16(Ah, bh1, c11, 0, 0, 0);
      c10 = __builtin_amdgcn_mfma_f32_16x16x32_f16(Al, bh0, c10, 0, 0, 0);
      c11 = __builtin_amdgcn_mfma_f32_16x16x32_f16(Al, bh1, c11, 0, 0, 0);
      c10 = __builtin_amdgcn_mfma_f32_16x16x32_f16(Ah, bl0, c10, 0, 0, 0);
      c11 = __builtin_amdgcn_mfma_f32_16x16x32_f16(Ah, bl1, c11, 0, 0, 0);
      f16x4 a20, a21;
#pragma unroll
      for (int r = 0; r < 4; ++r) {
        const float mj = Mja[r] + Mjb[r];
        float k0 = exp2f(fmaf(c10[r], si2, -(mi0 + mj)));
        float k1 = exp2f(fmaf(c11[r], si2, -(mi1 + mj)));
        Sp0 += k0;
        Sp1 += k1;
        a20[r] = (_Float16)k0;
        a21[r] = (_Float16)k1;
      }
      c2a0 = __builtin_amdgcn_mfma_f32_16x16x16f16(a20, Ba, c2a0, 0, 0, 0);
      c2b0 = __builtin_amdgcn_mfma_f32_16x16x16f16(a20, Bb, c2b0, 0, 0, 0);
      c2a1 = __builtin_amdgcn_mfma_f32_16x16x16f16(a21, Ba, c2a1, 0, 0, 0);
      c2b1 = __builtin_amdgcn_mfma_f32_16x16x16f16(a21, Bb, c2b1, 0, 0, 0);
    }
  }

  __syncthreads();  // all LDS reads done; sT overlay now safe

#pragma unroll
  for (int r = 0; r < 4; ++r) {
    sT[(wave * 32 + 4 * g + r) * 32 + li] = c2a0[r];
    sT[(wave * 32 + 4 * g + r) * 32 + 16 + li] = c2b0[r];
    sT[(wave * 32 + 16 + 4 * g + r) * 32 + li] = c2a1[r];
    sT[(wave * 32 + 16 + 4 * g + r) * 32 + 16 + li] = c2b1[r];
  }
  {
    float s0 = Sp0, s1 = Sp1;
    s0 += __shfl_xor(s0, 16, 64);
    s0 += __shfl_xor(s0, 32, 64);
    s1 += __shfl_xor(s1, 16, 64);
    s1 += __shfl_xor(s1, 32, 64);
    if (g == 0) {
      sS[wave * 32 + li] = s0;
      sS[wave * 32 + 16 + li] = s1;
    }
  }
  __syncthreads();

  const float c1f = inv * (1.f / NPART) * (1.f / REP);
  const float c2f = (1.f + inv) * (1.f / NPART) * (1.f / REP);
#pragma unroll
  for (int q = 0; q < 4; ++q) {
    const int v = q * 256 + tid;
    const int row = v >> 5, d = v & 31;
    const float T = sT[(0 * 32 + row) * 32 + d] + sT[(1 * 32 + row) * 32 + d] +
                    sT[(2 * 32 + row) * 32 + d] + sT[(3 * 32 + row) * 32 + d];
    const float S = sS[0 * 32 + row] + sS[1 * 32 + row] + sS[2 * 32 + row] +
                    sS[3 * 32 + row];
    const size_t idx = (size_t)(i0 + row) * DIM + d;
    unsafeAtomicAdd(&out[idx], c1f * S * X[idx] - c2f * T);
  }
}

// ---------------------------------------------------------------------------
// Fallback (used only if memset capture fails): single pass fp32, LDS tiles,
// writes out directly — no zeroing needed.
#define TJ 64
__global__ __launch_bounds__(256) void svgd_direct_kernel(const float* __restrict__ X,
                                                          const float* __restrict__ ls,
                                                          float* __restrict__ out) {
  __shared__ float4 sX[TJ * 8];
  const int tid = threadIdx.x;
  const int row = blockIdx.x * 256 + tid;
  const float lsv = ls[0];
  const float ls2 = lsv * lsv;
  const float inv2 = 0.5f / ls2;
  float4 xi[8];
  const float4* xr = reinterpret_cast<const float4*>(X + (size_t)row * DIM);
#pragma unroll
  for (int q = 0; q < 8; ++q) xi[q] = xr[q];
  float4 acc[8];
#pragma unroll
  for (int q = 0; q < 8; ++q) acc[q] = make_float4(0.f, 0.f, 0.f, 0.f);
  float S = 0.f;
  for (int jb = 0; jb < NPART; jb += TJ) {
    __syncthreads();
    const float4* src = reinterpret_cast<const float4*>(X + (size_t)jb * DIM);
    for (int t = tid; t < TJ * 8; t += 256) sX[t] = src[t];
    __syncthreads();
    for (int t = 0; t < TJ; ++t) {
      const float4* xj = &sX[t * 8];
      float4 v[8];
      float d0 = 0.f, d1 = 0.f, d2 = 0.f, d3 = 0.f;
#pragma unroll
      for (int q = 0; q < 8; ++q) {
        v[q] = xj[q];
        float ax = xi[q].x - v[q].x; d0 = fmaf(ax, ax, d0);
        float ay = xi[q].y - v[q].y; d1 = fmaf(ay, ay, d1);
        float az = xi[q].z - v[q].z; d2 = fmaf(az, az, d2);
        float aw = xi[q].w - v[q].w; d3 = fmaf(aw, aw, d3);
      }
      float k = __expf(-((d0 + d1) + (d2 + d3)) * inv2);
      S += k;
#pragma unroll
      for (int q = 0; q < 8; ++q) {
        acc[q].x = fmaf(k, v[q].x, acc[q].x);
        acc[q].y = fmaf(k, v[q].y, acc[q].y);
        acc[q].z = fmaf(k, v[q].z, acc[q].z);
        acc[q].w = fmaf(k, v[q].w, acc[q].w);
      }
    }
  }
  const float inv = 1.f / ls2;
  const float c1 = inv * S;
  const float c2 = 1.f + inv;
  float4* o = reinterpret_cast<float4*>(out + (size_t)row * DIM);
#pragma unroll
  for (int q = 0; q < 8; ++q) {
    float4 r;
    r.x = (c1 * xi[q].x - c2 * acc[q].x) * (1.f / NPART);
    r.y = (c1 * xi[q].y - c2 * acc[q].y) * (1.f / NPART);
    r.z = (c1 * xi[q].z - c2 * acc[q].z) * (1.f / NPART);
    r.w = (c1 * xi[q].w - c2 * acc[q].w) * (1.f / NPART);
    o[q] = r;
  }
}

// ---------------------------------------------------------------------------
extern "C" void kernel_launch(void* const* d_in, const int* in_sizes, int n_in,
                              void* d_out, int out_size, void* d_ws, size_t ws_size,
                              hipStream_t stream) {
  const float* X = (const float*)d_in[0];
  const float* ls = (const float*)d_in[1];
  float* out = (float*)d_out;
  (void)d_ws;
  (void)ws_size;

  hipError_t e =
      hipMemsetAsync(d_out, 0, (size_t)out_size * sizeof(float), stream);
  if (e == hipSuccess) {
    dim3 grid(NPART / 32, 8 * REP);
    svgd_onepass_kernel<<<grid, 256, 0, stream>>>(X, ls, out);
    return;
  }
  svgd_direct_kernel<<<NPART / 256, 256, 0, stream>>>(X, ls, out);
}

// Round 11
// 48.607 us; speedup vs baseline: 1.3396x; 1.3396x over previous
//
#include <hip/hip_runtime.h>

#define NPART 4096
#define DIM 32
#define LOG2E 1.44269504088896340736f

typedef _Float16 f16x8 __attribute__((ext_vector_type(8)));
typedef _Float16 f16x4 __attribute__((ext_vector_type(4)));
typedef float f32x4 __attribute__((ext_vector_type(4)));

// ---------------------------------------------------------------------------
// One-time prep: m2[r] = ||x_r||^2 * 0.5/ls^2 * log2e; XhP/XlP = hi/lo fp16
// split of X in MFMA-fragment element order (g*8+e -> d = e<4?4g+e:16+4g+e-4);
// XT[d][j] = (f16)X[j][d]. Conversion done ONCE here (not per i-block).
__global__ __launch_bounds__(256) void svgd_prep_kernel(
    const float* __restrict__ X, const float* __restrict__ ls,
    float* __restrict__ m2, _Float16* __restrict__ XhP,
    _Float16* __restrict__ XlP, _Float16* __restrict__ XT) {
  const int row = blockIdx.x * 256 + threadIdx.x;
  float v[DIM];
  const float4* xr = reinterpret_cast<const float4*>(X + (size_t)row * DIM);
#pragma unroll
  for (int q = 0; q < 8; ++q) {
    float4 a = xr[q];
    v[4 * q + 0] = a.x; v[4 * q + 1] = a.y; v[4 * q + 2] = a.z; v[4 * q + 3] = a.w;
  }
  float n = 0.f;
#pragma unroll
  for (int d = 0; d < DIM; ++d) n = fmaf(v[d], v[d], n);
  const float lsv = ls[0];
  const float inv = 1.f / (lsv * lsv);
  m2[row] = n * (0.5f * inv) * LOG2E;

  _Float16 h[DIM], l[DIM];
#pragma unroll
  for (int d = 0; d < DIM; ++d) {
    h[d] = (_Float16)v[d];
    l[d] = (_Float16)(v[d] - (float)h[d]);
  }
#pragma unroll
  for (int g = 0; g < 4; ++g) {
    f16x8 ph, pl;
#pragma unroll
    for (int e = 0; e < 8; ++e) {
      int d = (e < 4) ? (4 * g + e) : (16 + 4 * g + (e - 4));
      ph[e] = h[d];
      pl[e] = l[d];
    }
    *reinterpret_cast<f16x8*>(XhP + (size_t)row * DIM + g * 8) = ph;
    *reinterpret_cast<f16x8*>(XlP + (size_t)row * DIM + g * 8) = pl;
  }
#pragma unroll
  for (int d = 0; d < DIM; ++d) XT[(size_t)d * NPART + row] = h[d];
}

// ---------------------------------------------------------------------------
// Main: operands read directly from preconverted global (L2-resident, zero
// per-block conversion, zero staging LDS). LDS only for the 4-wave T/S
// reduce. High occupancy (8 blocks/CU, 32 waves/CU) hides L2 latency via TLP.
__global__ __launch_bounds__(256, 8) void svgd_main_kernel(
    const float* __restrict__ X, const _Float16* __restrict__ XhP,
    const _Float16* __restrict__ XlP, const _Float16* __restrict__ XT,
    const float* __restrict__ ls, const float* __restrict__ m2,
    float* __restrict__ out) {
  __shared__ float sT[4][32][32];
  __shared__ float sS[4][32];

  const int tid = threadIdx.x;
  const int lane = tid & 63;
  const int g = lane >> 4;    // 0..3
  const int li = lane & 15;   // 0..15
  const int wave = tid >> 6;  // 0..3
  const int i0 = blockIdx.x * 32;
  const int jbase = blockIdx.y * 512 + wave * 128;

  const float lsv = ls[0];
  const float inv = 1.f / (lsv * lsv);
  const float si2 = LOG2E * inv;

  // i-tile fragments (verified R3 lane mapping)
  f16x8 bh0, bl0, bh1, bl1;
  float mi0, mi1;
  {
    const int r0 = i0 + li, r1 = i0 + 16 + li;
    bh0 = *reinterpret_cast<const f16x8*>(XhP + (size_t)r0 * DIM + g * 8);
    bl0 = *reinterpret_cast<const f16x8*>(XlP + (size_t)r0 * DIM + g * 8);
    bh1 = *reinterpret_cast<const f16x8*>(XhP + (size_t)r1 * DIM + g * 8);
    bl1 = *reinterpret_cast<const f16x8*>(XlP + (size_t)r1 * DIM + g * 8);
    mi0 = m2[r0];
    mi1 = m2[r1];
  }

  f32x4 c2a0 = {0.f, 0.f, 0.f, 0.f}, c2b0 = {0.f, 0.f, 0.f, 0.f};
  f32x4 c2a1 = {0.f, 0.f, 0.f, 0.f}, c2b1 = {0.f, 0.f, 0.f, 0.f};
  float Sp0 = 0.f, Sp1 = 0.f;

#pragma unroll 2
  for (int itr = 0; itr < 8; ++itr) {
    const int j0 = jbase + itr * 16;
    f16x8 Ah = *reinterpret_cast<const f16x8*>(XhP + (size_t)(j0 + li) * DIM + g * 8);
    f16x8 Al = *reinterpret_cast<const f16x8*>(XlP + (size_t)(j0 + li) * DIM + g * 8);
    f16x4 Ba = *reinterpret_cast<const f16x4*>(XT + (size_t)li * NPART + j0 + 4 * g);
    f16x4 Bb = *reinterpret_cast<const f16x4*>(XT + (size_t)(16 + li) * NPART + j0 + 4 * g);
    float4 Mj = *reinterpret_cast<const float4*>(m2 + j0 + 4 * g);

    f32x4 c10 = {0.f, 0.f, 0.f, 0.f}, c11 = {0.f, 0.f, 0.f, 0.f};
    c10 = __builtin_amdgcn_mfma_f32_16x16x32_f16(Ah, bh0, c10, 0, 0, 0);
    c11 = __builtin_amdgcn_mfma_f32_16x16x32_f16(Ah, bh1, c11, 0, 0, 0);
    c10 = __builtin_amdgcn_mfma_f32_16x16x32_f16(Al, bh0, c10, 0, 0, 0);
    c11 = __builtin_amdgcn_mfma_f32_16x16x32_f16(Al, bh1, c11, 0, 0, 0);
    c10 = __builtin_amdgcn_mfma_f32_16x16x32_f16(Ah, bl0, c10, 0, 0, 0);
    c11 = __builtin_amdgcn_mfma_f32_16x16x32_f16(Ah, bl1, c11, 0, 0, 0);

    const float mj[4] = {Mj.x, Mj.y, Mj.z, Mj.w};
    f16x4 a20, a21;
#pragma unroll
    for (int r = 0; r < 4; ++r) {
      float k0 = exp2f(fmaf(c10[r], si2, -(mi0 + mj[r])));
      float k1 = exp2f(fmaf(c11[r], si2, -(mi1 + mj[r])));
      Sp0 += k0;
      Sp1 += k1;
      a20[r] = (_Float16)k0;
      a21[r] = (_Float16)k1;
    }
    c2a0 = __builtin_amdgcn_mfma_f32_16x16x16f16(a20, Ba, c2a0, 0, 0, 0);
    c2b0 = __builtin_amdgcn_mfma_f32_16x16x16f16(a20, Bb, c2b0, 0, 0, 0);
    c2a1 = __builtin_amdgcn_mfma_f32_16x16x16f16(a21, Ba, c2a1, 0, 0, 0);
    c2b1 = __builtin_amdgcn_mfma_f32_16x16x16f16(a21, Bb, c2b1, 0, 0, 0);
  }

  // block-level T/S reduce through LDS, then one atomic pass
#pragma unroll
  for (int r = 0; r < 4; ++r) {
    sT[wave][4 * g + r][li] = c2a0[r];
    sT[wave][4 * g + r][16 + li] = c2b0[r];
    sT[wave][16 + 4 * g + r][li] = c2a1[r];
    sT[wave][16 + 4 * g + r][16 + li] = c2b1[r];
  }
  {
    float s0 = Sp0, s1 = Sp1;
    s0 += __shfl_xor(s0, 16, 64);
    s0 += __shfl_xor(s0, 32, 64);
    s1 += __shfl_xor(s1, 16, 64);
    s1 += __shfl_xor(s1, 32, 64);
    if (g == 0) {
      sS[wave][li] = s0;
      sS[wave][16 + li] = s1;
    }
  }
  __syncthreads();

  const float c1f = inv * (1.f / NPART);
  const float c2f = (1.f + inv) * (1.f / NPART);
#pragma unroll
  for (int q = 0; q < 4; ++q) {
    const int v = q * 256 + tid;
    const int row = v >> 5, d = v & 31;
    const float T = sT[0][row][d] + sT[1][row][d] + sT[2][row][d] + sT[3][row][d];
    const float S = sS[0][row] + sS[1][row] + sS[2][row] + sS[3][row];
    const size_t idx = (size_t)(i0 + row) * DIM + d;
    unsafeAtomicAdd(&out[idx], c1f * S * X[idx] - c2f * T);
  }
}

// ---------------------------------------------------------------------------
// Fallback (memset-capture failure or tiny ws): single pass fp32, LDS tiles.
#define TJ 64
__global__ __launch_bounds__(256) void svgd_direct_kernel(const float* __restrict__ X,
                                                          const float* __restrict__ ls,
                                                          float* __restrict__ out) {
  __shared__ float4 sX[TJ * 8];
  const int tid = threadIdx.x;
  const int row = blockIdx.x * 256 + tid;
  const float lsv = ls[0];
  const float ls2 = lsv * lsv;
  const float inv2 = 0.5f / ls2;
  float4 xi[8];
  const float4* xr = reinterpret_cast<const float4*>(X + (size_t)row * DIM);
#pragma unroll
  for (int q = 0; q < 8; ++q) xi[q] = xr[q];
  float4 acc[8];
#pragma unroll
  for (int q = 0; q < 8; ++q) acc[q] = make_float4(0.f, 0.f, 0.f, 0.f);
  float S = 0.f;
  for (int jb = 0; jb < NPART; jb += TJ) {
    __syncthreads();
    const float4* src = reinterpret_cast<const float4*>(X + (size_t)jb * DIM);
    for (int t = tid; t < TJ * 8; t += 256) sX[t] = src[t];
    __syncthreads();
    for (int t = 0; t < TJ; ++t) {
      const float4* xj = &sX[t * 8];
      float4 v[8];
      float d0 = 0.f, d1 = 0.f, d2 = 0.f, d3 = 0.f;
#pragma unroll
      for (int q = 0; q < 8; ++q) {
        v[q] = xj[q];
        float ax = xi[q].x - v[q].x; d0 = fmaf(ax, ax, d0);
        float ay = xi[q].y - v[q].y; d1 = fmaf(ay, ay, d1);
        float az = xi[q].z - v[q].z; d2 = fmaf(az, az, d2);
        float aw = xi[q].w - v[q].w; d3 = fmaf(aw, aw, d3);
      }
      float k = __expf(-((d0 + d1) + (d2 + d3)) * inv2);
      S += k;
#pragma unroll
      for (int q = 0; q < 8; ++q) {
        acc[q].x = fmaf(k, v[q].x, acc[q].x);
        acc[q].y = fmaf(k, v[q].y, acc[q].y);
        acc[q].z = fmaf(k, v[q].z, acc[q].z);
        acc[q].w = fmaf(k, v[q].w, acc[q].w);
      }
    }
  }
  const float inv = 1.f / ls2;
  const float c1 = inv * S;
  const float c2 = 1.f + inv;
  float4* o = reinterpret_cast<float4*>(out + (size_t)row * DIM);
#pragma unroll
  for (int q = 0; q < 8; ++q) {
    float4 r;
    r.x = (c1 * xi[q].x - c2 * acc[q].x) * (1.f / NPART);
    r.y = (c1 * xi[q].y - c2 * acc[q].y) * (1.f / NPART);
    r.z = (c1 * xi[q].z - c2 * acc[q].z) * (1.f / NPART);
    r.w = (c1 * xi[q].w - c2 * acc[q].w) * (1.f / NPART);
    o[q] = r;
  }
}

// ---------------------------------------------------------------------------
extern "C" void kernel_launch(void* const* d_in, const int* in_sizes, int n_in,
                              void* d_out, int out_size, void* d_ws, size_t ws_size,
                              hipStream_t stream) {
  const float* X = (const float*)d_in[0];
  const float* ls = (const float*)d_in[1];
  float* out = (float*)d_out;
  float* ws = (float*)d_ws;

  // float words: m2 4096 | XhP 65536/2 | XlP | XT  (fp16 halves in fp32 words)
  const size_t fixed_f32 = 4096 + 3 * (NPART * DIM / 2);
  if (4 * fixed_f32 > ws_size) {
    svgd_direct_kernel<<<NPART / 256, 256, 0, stream>>>(X, ls, out);
    return;
  }

  hipError_t e =
      hipMemsetAsync(d_out, 0, (size_t)out_size * sizeof(float), stream);
  if (e != hipSuccess) {
    svgd_direct_kernel<<<NPART / 256, 256, 0, stream>>>(X, ls, out);
    return;
  }

  float* m2 = ws;
  _Float16* XhP = reinterpret_cast<_Float16*>(ws + 4096);
  _Float16* XlP = XhP + NPART * DIM;
  _Float16* XT = XlP + NPART * DIM;

  svgd_prep_kernel<<<NPART / 256, 256, 0, stream>>>(X, ls, m2, XhP, XlP, XT);
  dim3 grid(NPART / 32, 8);
  svgd_main_kernel<<<grid, 256, 0, stream>>>(X, XhP, XlP, XT, ls, m2, out);
}

// Round 12
// 32.561 us; speedup vs baseline: 1.9998x; 1.4928x over previous
//
#include <hip/hip_runtime.h>

#define NPART 4096
#define DIM 32
#define LOG2E 1.44269504088896340736f

typedef _Float16 f16x8 __attribute__((ext_vector_type(8)));
typedef _Float16 f16x4 __attribute__((ext_vector_type(4)));
typedef float f32x4 __attribute__((ext_vector_type(4)));

// ---------------------------------------------------------------------------
// One-time prep: m2[r] = ||x_r||^2 * 0.5/ls^2 * log2e; XhP/XlP = hi/lo fp16
// split of X in MFMA-fragment element order (g*8+e -> d = e<4?4g+e:16+4g+e-4);
// XT[d][j] = (f16)X[j][d]. Conversion done ONCE here (not per i-block).
__global__ __launch_bounds__(256) void svgd_prep_kernel(
    const float* __restrict__ X, const float* __restrict__ ls,
    float* __restrict__ m2, _Float16* __restrict__ XhP,
    _Float16* __restrict__ XlP, _Float16* __restrict__ XT) {
  const int row = blockIdx.x * 256 + threadIdx.x;
  float v[DIM];
  const float4* xr = reinterpret_cast<const float4*>(X + (size_t)row * DIM);
#pragma unroll
  for (int q = 0; q < 8; ++q) {
    float4 a = xr[q];
    v[4 * q + 0] = a.x; v[4 * q + 1] = a.y; v[4 * q + 2] = a.z; v[4 * q + 3] = a.w;
  }
  float n = 0.f;
#pragma unroll
  for (int d = 0; d < DIM; ++d) n = fmaf(v[d], v[d], n);
  const float lsv = ls[0];
  const float inv = 1.f / (lsv * lsv);
  m2[row] = n * (0.5f * inv) * LOG2E;

  _Float16 h[DIM], l[DIM];
#pragma unroll
  for (int d = 0; d < DIM; ++d) {
    h[d] = (_Float16)v[d];
    l[d] = (_Float16)(v[d] - (float)h[d]);
  }
#pragma unroll
  for (int g = 0; g < 4; ++g) {
    f16x8 ph, pl;
#pragma unroll
    for (int e = 0; e < 8; ++e) {
      int d = (e < 4) ? (4 * g + e) : (16 + 4 * g + (e - 4));
      ph[e] = h[d];
      pl[e] = l[d];
    }
    *reinterpret_cast<f16x8*>(XhP + (size_t)row * DIM + g * 8) = ph;
    *reinterpret_cast<f16x8*>(XlP + (size_t)row * DIM + g * 8) = pl;
  }
#pragma unroll
  for (int d = 0; d < DIM; ++d) XT[(size_t)d * NPART + row] = h[d];
}

// ---------------------------------------------------------------------------
// Main: operands read directly from preconverted global (L2-resident, zero
// per-block conversion VALU, zero staging LDS). LDS only for the 4-wave T/S
// reduce. Occupancy via block supply (grid 128x16 = 8 blocks/CU), NOT a
// forced VGPR bound (R11's (256,8) caused catastrophic spills).
__global__ __launch_bounds__(256, 4) void svgd_main_kernel(
    const float* __restrict__ X, const _Float16* __restrict__ XhP,
    const _Float16* __restrict__ XlP, const _Float16* __restrict__ XT,
    const float* __restrict__ ls, const float* __restrict__ m2,
    float* __restrict__ out) {
  __shared__ float sT[4][32][32];
  __shared__ float sS[4][32];

  const int tid = threadIdx.x;
  const int lane = tid & 63;
  const int g = lane >> 4;    // 0..3
  const int li = lane & 15;   // 0..15
  const int wave = tid >> 6;  // 0..3
  const int i0 = blockIdx.x * 32;
  const int jbase = blockIdx.y * 256 + wave * 64;

  const float lsv = ls[0];
  const float inv = 1.f / (lsv * lsv);
  const float si2 = LOG2E * inv;

  // i-tile fragments (verified R3 lane mapping)
  f16x8 bh0, bl0, bh1, bl1;
  float mi0, mi1;
  {
    const int r0 = i0 + li, r1 = i0 + 16 + li;
    bh0 = *reinterpret_cast<const f16x8*>(XhP + (size_t)r0 * DIM + g * 8);
    bl0 = *reinterpret_cast<const f16x8*>(XlP + (size_t)r0 * DIM + g * 8);
    bh1 = *reinterpret_cast<const f16x8*>(XhP + (size_t)r1 * DIM + g * 8);
    bl1 = *reinterpret_cast<const f16x8*>(XlP + (size_t)r1 * DIM + g * 8);
    mi0 = m2[r0];
    mi1 = m2[r1];
  }

  f32x4 c2a0 = {0.f, 0.f, 0.f, 0.f}, c2b0 = {0.f, 0.f, 0.f, 0.f};
  f32x4 c2a1 = {0.f, 0.f, 0.f, 0.f}, c2b1 = {0.f, 0.f, 0.f, 0.f};
  float Sp0 = 0.f, Sp1 = 0.f;

#pragma unroll
  for (int itr = 0; itr < 4; ++itr) {
    const int j0 = jbase + itr * 16;
    f16x8 Ah = *reinterpret_cast<const f16x8*>(XhP + (size_t)(j0 + li) * DIM + g * 8);
    f16x8 Al = *reinterpret_cast<const f16x8*>(XlP + (size_t)(j0 + li) * DIM + g * 8);
    f16x4 Ba = *reinterpret_cast<const f16x4*>(XT + (size_t)li * NPART + j0 + 4 * g);
    f16x4 Bb = *reinterpret_cast<const f16x4*>(XT + (size_t)(16 + li) * NPART + j0 + 4 * g);
    float4 Mj = *reinterpret_cast<const float4*>(m2 + j0 + 4 * g);

    f32x4 c10 = {0.f, 0.f, 0.f, 0.f}, c11 = {0.f, 0.f, 0.f, 0.f};
    c10 = __builtin_amdgcn_mfma_f32_16x16x32_f16(Ah, bh0, c10, 0, 0, 0);
    c11 = __builtin_amdgcn_mfma_f32_16x16x32_f16(Ah, bh1, c11, 0, 0, 0);
    c10 = __builtin_amdgcn_mfma_f32_16x16x32_f16(Al, bh0, c10, 0, 0, 0);
    c11 = __builtin_amdgcn_mfma_f32_16x16x32_f16(Al, bh1, c11, 0, 0, 0);
    c10 = __builtin_amdgcn_mfma_f32_16x16x32_f16(Ah, bl0, c10, 0, 0, 0);
    c11 = __builtin_amdgcn_mfma_f32_16x16x32_f16(Ah, bl1, c11, 0, 0, 0);

    const float mj[4] = {Mj.x, Mj.y, Mj.z, Mj.w};
    f16x4 a20, a21;
#pragma unroll
    for (int r = 0; r < 4; ++r) {
      float k0 = exp2f(fmaf(c10[r], si2, -(mi0 + mj[r])));
      float k1 = exp2f(fmaf(c11[r], si2, -(mi1 + mj[r])));
      Sp0 += k0;
      Sp1 += k1;
      a20[r] = (_Float16)k0;
      a21[r] = (_Float16)k1;
    }
    c2a0 = __builtin_amdgcn_mfma_f32_16x16x16f16(a20, Ba, c2a0, 0, 0, 0);
    c2b0 = __builtin_amdgcn_mfma_f32_16x16x16f16(a20, Bb, c2b0, 0, 0, 0);
    c2a1 = __builtin_amdgcn_mfma_f32_16x16x16f16(a21, Ba, c2a1, 0, 0, 0);
    c2b1 = __builtin_amdgcn_mfma_f32_16x16x16f16(a21, Bb, c2b1, 0, 0, 0);
  }

  // block-level T/S reduce through LDS, then one atomic pass
#pragma unroll
  for (int r = 0; r < 4; ++r) {
    sT[wave][4 * g + r][li] = c2a0[r];
    sT[wave][4 * g + r][16 + li] = c2b0[r];
    sT[wave][16 + 4 * g + r][li] = c2a1[r];
    sT[wave][16 + 4 * g + r][16 + li] = c2b1[r];
  }
  {
    float s0 = Sp0, s1 = Sp1;
    s0 += __shfl_xor(s0, 16, 64);
    s0 += __shfl_xor(s0, 32, 64);
    s1 += __shfl_xor(s1, 16, 64);
    s1 += __shfl_xor(s1, 32, 64);
    if (g == 0) {
      sS[wave][li] = s0;
      sS[wave][16 + li] = s1;
    }
  }
  __syncthreads();

  const float c1f = inv * (1.f / NPART);
  const float c2f = (1.f + inv) * (1.f / NPART);
#pragma unroll
  for (int q = 0; q < 4; ++q) {
    const int v = q * 256 + tid;
    const int row = v >> 5, d = v & 31;
    const float T = sT[0][row][d] + sT[1][row][d] + sT[2][row][d] + sT[3][row][d];
    const float S = sS[0][row] + sS[1][row] + sS[2][row] + sS[3][row];
    const size_t idx = (size_t)(i0 + row) * DIM + d;
    unsafeAtomicAdd(&out[idx], c1f * S * X[idx] - c2f * T);
  }
}

// ---------------------------------------------------------------------------
// Fallback (memset-capture failure or tiny ws): single pass fp32, LDS tiles.
#define TJ 64
__global__ __launch_bounds__(256) void svgd_direct_kernel(const float* __restrict__ X,
                                                          const float* __restrict__ ls,
                                                          float* __restrict__ out) {
  __shared__ float4 sX[TJ * 8];
  const int tid = threadIdx.x;
  const int row = blockIdx.x * 256 + tid;
  const float lsv = ls[0];
  const float ls2 = lsv * lsv;
  const float inv2 = 0.5f / ls2;
  float4 xi[8];
  const float4* xr = reinterpret_cast<const float4*>(X + (size_t)row * DIM);
#pragma unroll
  for (int q = 0; q < 8; ++q) xi[q] = xr[q];
  float4 acc[8];
#pragma unroll
  for (int q = 0; q < 8; ++q) acc[q] = make_float4(0.f, 0.f, 0.f, 0.f);
  float S = 0.f;
  for (int jb = 0; jb < NPART; jb += TJ) {
    __syncthreads();
    const float4* src = reinterpret_cast<const float4*>(X + (size_t)jb * DIM);
    for (int t = tid; t < TJ * 8; t += 256) sX[t] = src[t];
    __syncthreads();
    for (int t = 0; t < TJ; ++t) {
      const float4* xj = &sX[t * 8];
      float4 v[8];
      float d0 = 0.f, d1 = 0.f, d2 = 0.f, d3 = 0.f;
#pragma unroll
      for (int q = 0; q < 8; ++q) {
        v[q] = xj[q];
        float ax = xi[q].x - v[q].x; d0 = fmaf(ax, ax, d0);
        float ay = xi[q].y - v[q].y; d1 = fmaf(ay, ay, d1);
        float az = xi[q].z - v[q].z; d2 = fmaf(az, az, d2);
        float aw = xi[q].w - v[q].w; d3 = fmaf(aw, aw, d3);
      }
      float k = __expf(-((d0 + d1) + (d2 + d3)) * inv2);
      S += k;
#pragma unroll
      for (int q = 0; q < 8; ++q) {
        acc[q].x = fmaf(k, v[q].x, acc[q].x);
        acc[q].y = fmaf(k, v[q].y, acc[q].y);
        acc[q].z = fmaf(k, v[q].z, acc[q].z);
        acc[q].w = fmaf(k, v[q].w, acc[q].w);
      }
    }
  }
  const float inv = 1.f / ls2;
  const float c1 = inv * S;
  const float c2 = 1.f + inv;
  float4* o = reinterpret_cast<float4*>(out + (size_t)row * DIM);
#pragma unroll
  for (int q = 0; q < 8; ++q) {
    float4 r;
    r.x = (c1 * xi[q].x - c2 * acc[q].x) * (1.f / NPART);
    r.y = (c1 * xi[q].y - c2 * acc[q].y) * (1.f / NPART);
    r.z = (c1 * xi[q].z - c2 * acc[q].z) * (1.f / NPART);
    r.w = (c1 * xi[q].w - c2 * acc[q].w) * (1.f / NPART);
    o[q] = r;
  }
}

// ---------------------------------------------------------------------------
extern "C" void kernel_launch(void* const* d_in, const int* in_sizes, int n_in,
                              void* d_out, int out_size, void* d_ws, size_t ws_size,
                              hipStream_t stream) {
  const float* X = (const float*)d_in[0];
  const float* ls = (const float*)d_in[1];
  float* out = (float*)d_out;
  float* ws = (float*)d_ws;

  // float words: m2 4096 | XhP 65536/2 | XlP | XT  (fp16 halves in fp32 words)
  const size_t fixed_f32 = 4096 + 3 * (NPART * DIM / 2);
  if (4 * fixed_f32 > ws_size) {
    svgd_direct_kernel<<<NPART / 256, 256, 0, stream>>>(X, ls, out);
    return;
  }

  hipError_t e =
      hipMemsetAsync(d_out, 0, (size_t)out_size * sizeof(float), stream);
  if (e != hipSuccess) {
    svgd_direct_kernel<<<NPART / 256, 256, 0, stream>>>(X, ls, out);
    return;
  }

  float* m2 = ws;
  _Float16* XhP = reinterpret_cast<_Float16*>(ws + 4096);
  _Float16* XlP = XhP + NPART * DIM;
  _Float16* XT = XlP + NPART * DIM;

  svgd_prep_kernel<<<NPART / 256, 256, 0, stream>>>(X, ls, m2, XhP, XlP, XT);
  dim3 grid(NPART / 32, 16);
  svgd_main_kernel<<<grid, 256, 0, stream>>>(X, XhP, XlP, XT, ls, m2, out);
}

// Round 13
// 25.935 us; speedup vs baseline: 2.5107x; 1.2555x over previous
//
#include <hip/hip_runtime.h>

#define NPART 4096
#define DIM 32
#define LOG2E 1.44269504088896340736f
#define SHSTR 36  // padded row stride (halves) for sHi/sLo: 72B = 18 dwords,
                  // gcd(18,32)=2 -> 16 li-rows cover all 16 even banks (~2-way)
                  // vs old 32 (64B = 16 dwords -> banks {0,16}, 16-way).

typedef _Float16 f16x8 __attribute__((ext_vector_type(8)));
typedef _Float16 f16x4 __attribute__((ext_vector_type(4)));
typedef float f32x4 __attribute__((ext_vector_type(4)));

// ---------------------------------------------------------------------------
// Single-pass kernel (R8 skeleton, bank-conflict-fixed LDS layout).
// Block = 32 i-rows x 512 j-cols; 4 stages of 128 j-rows converted in-LDS;
// out pre-zeroed by memset node; atomic accumulate of linear contribution.
__global__ __launch_bounds__(256, 4) void svgd_onepass_kernel(
    const float* __restrict__ X, const float* __restrict__ ls,
    float* __restrict__ out) {
  // LDS carve (28672 B). sT overlays sHi+sLo (valid after final barrier).
  __shared__ __align__(16) unsigned char smem[28672];
  _Float16* sHi = (_Float16*)smem;             // [128][SHSTR] frag-order hi
  _Float16* sLo = (_Float16*)(smem + 9216);    // [128][SHSTR] frag-order lo
  _Float16* sXT = (_Float16*)(smem + 18432);   // [32][136] transpose (padded)
  float* sM2 = (float*)(smem + 27136);         // [2][128] norm partials
  float* sS = (float*)(smem + 28160);          // [4][32]
  float* sT = (float*)smem;                    // overlay [4][32][32]

  const int tid = threadIdx.x;
  const int lane = tid & 63;
  const int g = lane >> 4;    // 0..3
  const int li = lane & 15;   // 0..15
  const int wave = tid >> 6;  // 0..3
  const int i0 = blockIdx.x * 32;
  const int jb0 = blockIdx.y * 512;

  const float lsv = ls[0];
  const float inv = 1.f / (lsv * lsv);
  const float si2 = LOG2E * inv;
  const float hm = 0.5f * si2;

  const float4* X4 = (const float4*)X;

  // ---- i-tile fragments + norms, in registers (verified R3 lane mapping) --
  f16x8 bh0, bl0, bh1, bl1;
  float mi0, mi1;
  {
    const int r0 = i0 + li, r1 = i0 + 16 + li;
    float4 a0 = X4[(size_t)r0 * 8 + g], b0 = X4[(size_t)r0 * 8 + 4 + g];
    float4 a1 = X4[(size_t)r1 * 8 + g], b1 = X4[(size_t)r1 * 8 + 4 + g];
    float t0[8] = {a0.x, a0.y, a0.z, a0.w, b0.x, b0.y, b0.z, b0.w};
    float t1[8] = {a1.x, a1.y, a1.z, a1.w, b1.x, b1.y, b1.z, b1.w};
    float n0 = 0.f, n1 = 0.f;
#pragma unroll
    for (int e = 0; e < 8; ++e) {
      n0 = fmaf(t0[e], t0[e], n0);
      n1 = fmaf(t1[e], t1[e], n1);
      _Float16 h0 = (_Float16)t0[e];
      _Float16 h1 = (_Float16)t1[e];
      bh0[e] = h0; bl0[e] = (_Float16)(t0[e] - (float)h0);
      bh1[e] = h1; bl1[e] = (_Float16)(t1[e] - (float)h1);
    }
    n0 += __shfl_xor(n0, 16, 64);
    n0 += __shfl_xor(n0, 32, 64);
    n1 += __shfl_xor(n1, 16, 64);
    n1 += __shfl_xor(n1, 32, 64);
    mi0 = n0 * hm;
    mi1 = n1 * hm;
  }

  f32x4 c2a0 = {0.f, 0.f, 0.f, 0.f}, c2b0 = {0.f, 0.f, 0.f, 0.f};
  f32x4 c2a1 = {0.f, 0.f, 0.f, 0.f}, c2b1 = {0.f, 0.f, 0.f, 0.f};
  float Sp0 = 0.f, Sp1 = 0.f;

  // ---- 4 stages of 128 j-rows: convert to LDS, then 2 COMP iters/wave ----
#pragma unroll
  for (int s = 0; s < 4; ++s) {
    __syncthreads();  // prior-stage consumers done
    {
      const int r = tid >> 1, sub = tid & 1;
      const int row = jb0 + s * 128 + r;
      const float4* src = X4 + (size_t)row * 8 + sub * 4;
      float4 va = src[0], vb = src[1], vc = src[2], vd = src[3];
      float tv[16] = {va.x, va.y, va.z, va.w, vb.x, vb.y, vb.z, vb.w,
                      vc.x, vc.y, vc.z, vc.w, vd.x, vd.y, vd.z, vd.w};
      _Float16 h[16], l[16];
      float nrm = 0.f;
#pragma unroll
      for (int e = 0; e < 16; ++e) {
        nrm = fmaf(tv[e], tv[e], nrm);
        _Float16 hh = (_Float16)tv[e];
        h[e] = hh;
        l[e] = (_Float16)(tv[e] - (float)hh);
      }
      sM2[sub * 128 + r] = nrm * hm;
#pragma unroll
      for (int gq = 0; gq < 4; ++gq) {
        f16x4 ph, pl;
#pragma unroll
        for (int e = 0; e < 4; ++e) { ph[e] = h[4 * gq + e]; pl[e] = l[4 * gq + e]; }
        *(f16x4*)(sHi + r * SHSTR + gq * 8 + sub * 4) = ph;
        *(f16x4*)(sLo + r * SHSTR + gq * 8 + sub * 4) = pl;
      }
#pragma unroll
      for (int e = 0; e < 16; ++e) sXT[(16 * sub + e) * 136 + r] = h[e];
    }
    __syncthreads();

#pragma unroll
    for (int it = 0; it < 2; ++it) {
      const int jloc = wave * 32 + it * 16;
      const _Float16* hb = sHi + (jloc + li) * SHSTR + g * 8;
      const _Float16* lb = sLo + (jloc + li) * SHSTR + g * 8;
      f16x4 AhL = *(const f16x4*)(hb);
      f16x4 AhH = *(const f16x4*)(hb + 4);
      f16x4 AlL = *(const f16x4*)(lb);
      f16x4 AlH = *(const f16x4*)(lb + 4);
      f16x8 Ah = __builtin_shufflevector(AhL, AhH, 0, 1, 2, 3, 4, 5, 6, 7);
      f16x8 Al = __builtin_shufflevector(AlL, AlH, 0, 1, 2, 3, 4, 5, 6, 7);
      f16x4 Ba = *(const f16x4*)(sXT + li * 136 + jloc + 4 * g);
      f16x4 Bb = *(const f16x4*)(sXT + (16 + li) * 136 + jloc + 4 * g);
      f32x4 Mja = *(const f32x4*)(sM2 + jloc + 4 * g);
      f32x4 Mjb = *(const f32x4*)(sM2 + 128 + jloc + 4 * g);

      f32x4 c10 = {0.f, 0.f, 0.f, 0.f}, c11 = {0.f, 0.f, 0.f, 0.f};
      c10 = __builtin_amdgcn_mfma_f32_16x16x32_f16(Ah, bh0, c10, 0, 0, 0);
      c11 = __builtin_amdgcn_mfma_f32_16x16x32_f16(Ah, bh1, c11, 0, 0, 0);
      c10 = __builtin_amdgcn_mfma_f32_16x16x32_f16(Al, bh0, c10, 0, 0, 0);
      c11 = __builtin_amdgcn_mfma_f32_16x16x32_f16(Al, bh1, c11, 0, 0, 0);
      c10 = __builtin_amdgcn_mfma_f32_16x16x32_f16(Ah, bl0, c10, 0, 0, 0);
      c11 = __builtin_amdgcn_mfma_f32_16x16x32_f16(Ah, bl1, c11, 0, 0, 0);
      f16x4 a20, a21;
#pragma unroll
      for (int r = 0; r < 4; ++r) {
        const float mj = Mja[r] + Mjb[r];
        float k0 = exp2f(fmaf(c10[r], si2, -(mi0 + mj)));
        float k1 = exp2f(fmaf(c11[r], si2, -(mi1 + mj)));
        Sp0 += k0;
        Sp1 += k1;
        a20[r] = (_Float16)k0;
        a21[r] = (_Float16)k1;
      }
      c2a0 = __builtin_amdgcn_mfma_f32_16x16x16f16(a20, Ba, c2a0, 0, 0, 0);
      c2b0 = __builtin_amdgcn_mfma_f32_16x16x16f16(a20, Bb, c2b0, 0, 0, 0);
      c2a1 = __builtin_amdgcn_mfma_f32_16x16x16f16(a21, Ba, c2a1, 0, 0, 0);
      c2b1 = __builtin_amdgcn_mfma_f32_16x16x16f16(a21, Bb, c2b1, 0, 0, 0);
    }
  }

  __syncthreads();  // all LDS reads done; sT overlay now safe

#pragma unroll
  for (int r = 0; r < 4; ++r) {
    sT[(wave * 32 + 4 * g + r) * 32 + li] = c2a0[r];
    sT[(wave * 32 + 4 * g + r) * 32 + 16 + li] = c2b0[r];
    sT[(wave * 32 + 16 + 4 * g + r) * 32 + li] = c2a1[r];
    sT[(wave * 32 + 16 + 4 * g + r) * 32 + 16 + li] = c2b1[r];
  }
  {
    float s0 = Sp0, s1 = Sp1;
    s0 += __shfl_xor(s0, 16, 64);
    s0 += __shfl_xor(s0, 32, 64);
    s1 += __shfl_xor(s1, 16, 64);
    s1 += __shfl_xor(s1, 32, 64);
    if (g == 0) {
      sS[wave * 32 + li] = s0;
      sS[wave * 32 + 16 + li] = s1;
    }
  }
  __syncthreads();

  const float c1f = inv * (1.f / NPART);
  const float c2f = (1.f + inv) * (1.f / NPART);
#pragma unroll
  for (int q = 0; q < 4; ++q) {
    const int v = q * 256 + tid;
    const int row = v >> 5, d = v & 31;
    const float T = sT[(0 * 32 + row) * 32 + d] + sT[(1 * 32 + row) * 32 + d] +
                    sT[(2 * 32 + row) * 32 + d] + sT[(3 * 32 + row) * 32 + d];
    const float S = sS[0 * 32 + row] + sS[1 * 32 + row] + sS[2 * 32 + row] +
                    sS[3 * 32 + row];
    const size_t idx = (size_t)(i0 + row) * DIM + d;
    unsafeAtomicAdd(&out[idx], c1f * S * X[idx] - c2f * T);
  }
}

// ---------------------------------------------------------------------------
// Fallback (used only if memset capture fails): single pass fp32, LDS tiles,
// writes out directly — no zeroing needed.
#define TJ 64
__global__ __launch_bounds__(256) void svgd_direct_kernel(const float* __restrict__ X,
                                                          const float* __restrict__ ls,
                                                          float* __restrict__ out) {
  __shared__ float4 sX[TJ * 8];
  const int tid = threadIdx.x;
  const int row = blockIdx.x * 256 + tid;
  const float lsv = ls[0];
  const float ls2 = lsv * lsv;
  const float inv2 = 0.5f / ls2;
  float4 xi[8];
  const float4* xr = reinterpret_cast<const float4*>(X + (size_t)row * DIM);
#pragma unroll
  for (int q = 0; q < 8; ++q) xi[q] = xr[q];
  float4 acc[8];
#pragma unroll
  for (int q = 0; q < 8; ++q) acc[q] = make_float4(0.f, 0.f, 0.f, 0.f);
  float S = 0.f;
  for (int jb = 0; jb < NPART; jb += TJ) {
    __syncthreads();
    const float4* src = reinterpret_cast<const float4*>(X + (size_t)jb * DIM);
    for (int t = tid; t < TJ * 8; t += 256) sX[t] = src[t];
    __syncthreads();
    for (int t = 0; t < TJ; ++t) {
      const float4* xj = &sX[t * 8];
      float4 v[8];
      float d0 = 0.f, d1 = 0.f, d2 = 0.f, d3 = 0.f;
#pragma unroll
      for (int q = 0; q < 8; ++q) {
        v[q] = xj[q];
        float ax = xi[q].x - v[q].x; d0 = fmaf(ax, ax, d0);
        float ay = xi[q].y - v[q].y; d1 = fmaf(ay, ay, d1);
        float az = xi[q].z - v[q].z; d2 = fmaf(az, az, d2);
        float aw = xi[q].w - v[q].w; d3 = fmaf(aw, aw, d3);
      }
      float k = __expf(-((d0 + d1) + (d2 + d3)) * inv2);
      S += k;
#pragma unroll
      for (int q = 0; q < 8; ++q) {
        acc[q].x = fmaf(k, v[q].x, acc[q].x);
        acc[q].y = fmaf(k, v[q].y, acc[q].y);
        acc[q].z = fmaf(k, v[q].z, acc[q].z);
        acc[q].w = fmaf(k, v[q].w, acc[q].w);
      }
    }
  }
  const float inv = 1.f / ls2;
  const float c1 = inv * S;
  const float c2 = 1.f + inv;
  float4* o = reinterpret_cast<float4*>(out + (size_t)row * DIM);
#pragma unroll
  for (int q = 0; q < 8; ++q) {
    float4 r;
    r.x = (c1 * xi[q].x - c2 * acc[q].x) * (1.f / NPART);
    r.y = (c1 * xi[q].y - c2 * acc[q].y) * (1.f / NPART);
    r.z = (c1 * xi[q].z - c2 * acc[q].z) * (1.f / NPART);
    r.w = (c1 * xi[q].w - c2 * acc[q].w) * (1.f / NPART);
    o[q] = r;
  }
}

// ---------------------------------------------------------------------------
extern "C" void kernel_launch(void* const* d_in, const int* in_sizes, int n_in,
                              void* d_out, int out_size, void* d_ws, size_t ws_size,
                              hipStream_t stream) {
  const float* X = (const float*)d_in[0];
  const float* ls = (const float*)d_in[1];
  float* out = (float*)d_out;
  (void)d_ws;
  (void)ws_size;

  hipError_t e =
      hipMemsetAsync(d_out, 0, (size_t)out_size * sizeof(float), stream);
  if (e == hipSuccess) {
    dim3 grid(NPART / 32, 8);
    svgd_onepass_kernel<<<grid, 256, 0, stream>>>(X, ls, out);
    return;
  }
  svgd_direct_kernel<<<NPART / 256, 256, 0, stream>>>(X, ls, out);
}

// Round 14
// 25.722 us; speedup vs baseline: 2.5315x; 1.0083x over previous
//
#include <hip/hip_runtime.h>

#define NPART 4096
#define DIM 32
#define LOG2E 1.44269504088896340736f
#define SHSTR 36  // padded row stride (halves) for sHi/sLo (R13-verified)

typedef _Float16 f16x8 __attribute__((ext_vector_type(8)));
typedef _Float16 f16x4 __attribute__((ext_vector_type(4)));
typedef float f32x4 __attribute__((ext_vector_type(4)));

// ---------------------------------------------------------------------------
// Single-pass kernel, 8-blocks/CU variant: 8 stages x 64 j-rows keeps LDS at
// 16.9 KB so 8 blocks co-reside per CU (vs 4 at R13's 28.7 KB) — barrier and
// memory stalls of one block overlap with compute of the other 7.
// out pre-zeroed by memset node; atomic accumulate of linear contribution.
__global__ __launch_bounds__(256, 4) void svgd_onepass_kernel(
    const float* __restrict__ X, const float* __restrict__ ls,
    float* __restrict__ out) {
  // LDS carve (16896 B). sT overlays staging buffers after the final barrier.
  __shared__ __align__(16) unsigned char smem[16896];
  _Float16* sHi = (_Float16*)smem;             // [64][SHSTR] frag-order hi
  _Float16* sLo = (_Float16*)(smem + 4608);    // [64][SHSTR] frag-order lo
  _Float16* sXT = (_Float16*)(smem + 9216);    // [32][72] transpose (padded)
  float* sM2 = (float*)(smem + 13824);         // [64] scaled norms
  float* sT = (float*)smem;                    // overlay [4][32][32] = 16384 B
  float* sS = (float*)(smem + 16384);          // [4][32] (outside overlay)

  const int tid = threadIdx.x;
  const int lane = tid & 63;
  const int g = lane >> 4;    // 0..3
  const int li = lane & 15;   // 0..15
  const int wave = tid >> 6;  // 0..3
  const int i0 = blockIdx.x * 32;
  const int jb0 = blockIdx.y * 512;

  const float lsv = ls[0];
  const float inv = 1.f / (lsv * lsv);
  const float si2 = LOG2E * inv;
  const float hm = 0.5f * si2;

  const float4* X4 = (const float4*)X;

  // ---- i-tile fragments + norms, in registers (verified R3 lane mapping) --
  f16x8 bh0, bl0, bh1, bl1;
  float mi0, mi1;
  {
    const int r0 = i0 + li, r1 = i0 + 16 + li;
    float4 a0 = X4[(size_t)r0 * 8 + g], b0 = X4[(size_t)r0 * 8 + 4 + g];
    float4 a1 = X4[(size_t)r1 * 8 + g], b1 = X4[(size_t)r1 * 8 + 4 + g];
    float t0[8] = {a0.x, a0.y, a0.z, a0.w, b0.x, b0.y, b0.z, b0.w};
    float t1[8] = {a1.x, a1.y, a1.z, a1.w, b1.x, b1.y, b1.z, b1.w};
    float n0 = 0.f, n1 = 0.f;
#pragma unroll
    for (int e = 0; e < 8; ++e) {
      n0 = fmaf(t0[e], t0[e], n0);
      n1 = fmaf(t1[e], t1[e], n1);
      _Float16 h0 = (_Float16)t0[e];
      _Float16 h1 = (_Float16)t1[e];
      bh0[e] = h0; bl0[e] = (_Float16)(t0[e] - (float)h0);
      bh1[e] = h1; bl1[e] = (_Float16)(t1[e] - (float)h1);
    }
    n0 += __shfl_xor(n0, 16, 64);
    n0 += __shfl_xor(n0, 32, 64);
    n1 += __shfl_xor(n1, 16, 64);
    n1 += __shfl_xor(n1, 32, 64);
    mi0 = n0 * hm;
    mi1 = n1 * hm;
  }

  f32x4 c2a0 = {0.f, 0.f, 0.f, 0.f}, c2b0 = {0.f, 0.f, 0.f, 0.f};
  f32x4 c2a1 = {0.f, 0.f, 0.f, 0.f}, c2b1 = {0.f, 0.f, 0.f, 0.f};
  float Sp0 = 0.f, Sp1 = 0.f;

  // ---- 8 stages of 64 j-rows: convert to LDS, then 1 COMP iter/wave ----
  for (int s = 0; s < 8; ++s) {
    __syncthreads();  // prior-stage consumers done
    {
      const int r = tid >> 2, ss = tid & 3;  // r: row-in-stage 0..63
      const int row = jb0 + s * 64 + r;
      float4 a = X4[(size_t)row * 8 + ss];
      float4 b = X4[(size_t)row * 8 + 4 + ss];
      float tv[8] = {a.x, a.y, a.z, a.w, b.x, b.y, b.z, b.w};
      _Float16 h[8];
      f16x4 pl0, pl1;
      float nrm = 0.f;
#pragma unroll
      for (int e = 0; e < 8; ++e) {
        nrm = fmaf(tv[e], tv[e], nrm);
        _Float16 hh = (_Float16)tv[e];
        h[e] = hh;
        _Float16 ll = (_Float16)(tv[e] - (float)hh);
        if (e < 4) pl0[e] = ll; else pl1[e - 4] = ll;
      }
      // fragment g == ss for this thread's 8 elems (d = 4ss+e / 16+4ss+e-4)
      f16x4 ph0 = {h[0], h[1], h[2], h[3]};
      f16x4 ph1 = {h[4], h[5], h[6], h[7]};
      *(f16x4*)(sHi + r * SHSTR + ss * 8) = ph0;
      *(f16x4*)(sHi + r * SHSTR + ss * 8 + 4) = ph1;
      *(f16x4*)(sLo + r * SHSTR + ss * 8) = pl0;
      *(f16x4*)(sLo + r * SHSTR + ss * 8 + 4) = pl1;
#pragma unroll
      for (int e = 0; e < 8; ++e) {
        const int d = (e < 4) ? (4 * ss + e) : (16 + 4 * ss + (e - 4));
        sXT[d * 72 + r] = h[e];
      }
      nrm += __shfl_xor(nrm, 1, 64);
      nrm += __shfl_xor(nrm, 2, 64);
      if (ss == 0) sM2[r] = nrm * hm;
    }
    __syncthreads();

    {
      const int jloc = wave * 16;
      const _Float16* hb = sHi + (jloc + li) * SHSTR + g * 8;
      const _Float16* lb = sLo + (jloc + li) * SHSTR + g * 8;
      f16x4 AhL = *(const f16x4*)(hb);
      f16x4 AhH = *(const f16x4*)(hb + 4);
      f16x4 AlL = *(const f16x4*)(lb);
      f16x4 AlH = *(const f16x4*)(lb + 4);
      f16x8 Ah = __builtin_shufflevector(AhL, AhH, 0, 1, 2, 3, 4, 5, 6, 7);
      f16x8 Al = __builtin_shufflevector(AlL, AlH, 0, 1, 2, 3, 4, 5, 6, 7);
      f16x4 Ba = *(const f16x4*)(sXT + li * 72 + jloc + 4 * g);
      f16x4 Bb = *(const f16x4*)(sXT + (16 + li) * 72 + jloc + 4 * g);
      f32x4 Mj = *(const f32x4*)(sM2 + jloc + 4 * g);

      f32x4 c10 = {0.f, 0.f, 0.f, 0.f}, c11 = {0.f, 0.f, 0.f, 0.f};
      c10 = __builtin_amdgcn_mfma_f32_16x16x32_f16(Ah, bh0, c10, 0, 0, 0);
      c11 = __builtin_amdgcn_mfma_f32_16x16x32_f16(Ah, bh1, c11, 0, 0, 0);
      c10 = __builtin_amdgcn_mfma_f32_16x16x32_f16(Al, bh0, c10, 0, 0, 0);
      c11 = __builtin_amdgcn_mfma_f32_16x16x32_f16(Al, bh1, c11, 0, 0, 0);
      c10 = __builtin_amdgcn_mfma_f32_16x16x32_f16(Ah, bl0, c10, 0, 0, 0);
      c11 = __builtin_amdgcn_mfma_f32_16x16x32_f16(Ah, bl1, c11, 0, 0, 0);
      f16x4 a20, a21;
#pragma unroll
      for (int r = 0; r < 4; ++r) {
        float k0 = exp2f(fmaf(c10[r], si2, -(mi0 + Mj[r])));
        float k1 = exp2f(fmaf(c11[r], si2, -(mi1 + Mj[r])));
        Sp0 += k0;
        Sp1 += k1;
        a20[r] = (_Float16)k0;
        a21[r] = (_Float16)k1;
      }
      c2a0 = __builtin_amdgcn_mfma_f32_16x16x16f16(a20, Ba, c2a0, 0, 0, 0);
      c2b0 = __builtin_amdgcn_mfma_f32_16x16x16f16(a20, Bb, c2b0, 0, 0, 0);
      c2a1 = __builtin_amdgcn_mfma_f32_16x16x16f16(a21, Ba, c2a1, 0, 0, 0);
      c2b1 = __builtin_amdgcn_mfma_f32_16x16x16f16(a21, Bb, c2b1, 0, 0, 0);
    }
  }

  __syncthreads();  // all LDS reads done; sT overlay now safe

#pragma unroll
  for (int r = 0; r < 4; ++r) {
    sT[(wave * 32 + 4 * g + r) * 32 + li] = c2a0[r];
    sT[(wave * 32 + 4 * g + r) * 32 + 16 + li] = c2b0[r];
    sT[(wave * 32 + 16 + 4 * g + r) * 32 + li] = c2a1[r];
    sT[(wave * 32 + 16 + 4 * g + r) * 32 + 16 + li] = c2b1[r];
  }
  {
    float s0 = Sp0, s1 = Sp1;
    s0 += __shfl_xor(s0, 16, 64);
    s0 += __shfl_xor(s0, 32, 64);
    s1 += __shfl_xor(s1, 16, 64);
    s1 += __shfl_xor(s1, 32, 64);
    if (g == 0) {
      sS[wave * 32 + li] = s0;
      sS[wave * 32 + 16 + li] = s1;
    }
  }
  __syncthreads();

  const float c1f = inv * (1.f / NPART);
  const float c2f = (1.f + inv) * (1.f / NPART);
#pragma unroll
  for (int q = 0; q < 4; ++q) {
    const int v = q * 256 + tid;
    const int row = v >> 5, d = v & 31;
    const float T = sT[(0 * 32 + row) * 32 + d] + sT[(1 * 32 + row) * 32 + d] +
                    sT[(2 * 32 + row) * 32 + d] + sT[(3 * 32 + row) * 32 + d];
    const float S = sS[0 * 32 + row] + sS[1 * 32 + row] + sS[2 * 32 + row] +
                    sS[3 * 32 + row];
    const size_t idx = (size_t)(i0 + row) * DIM + d;
    unsafeAtomicAdd(&out[idx], c1f * S * X[idx] - c2f * T);
  }
}

// ---------------------------------------------------------------------------
// Fallback (used only if memset capture fails): single pass fp32, LDS tiles,
// writes out directly — no zeroing needed.
#define TJ 64
__global__ __launch_bounds__(256) void svgd_direct_kernel(const float* __restrict__ X,
                                                          const float* __restrict__ ls,
                                                          float* __restrict__ out) {
  __shared__ float4 sX[TJ * 8];
  const int tid = threadIdx.x;
  const int row = blockIdx.x * 256 + tid;
  const float lsv = ls[0];
  const float ls2 = lsv * lsv;
  const float inv2 = 0.5f / ls2;
  float4 xi[8];
  const float4* xr = reinterpret_cast<const float4*>(X + (size_t)row * DIM);
#pragma unroll
  for (int q = 0; q < 8; ++q) xi[q] = xr[q];
  float4 acc[8];
#pragma unroll
  for (int q = 0; q < 8; ++q) acc[q] = make_float4(0.f, 0.f, 0.f, 0.f);
  float S = 0.f;
  for (int jb = 0; jb < NPART; jb += TJ) {
    __syncthreads();
    const float4* src = reinterpret_cast<const float4*>(X + (size_t)jb * DIM);
    for (int t = tid; t < TJ * 8; t += 256) sX[t] = src[t];
    __syncthreads();
    for (int t = 0; t < TJ; ++t) {
      const float4* xj = &sX[t * 8];
      float4 v[8];
      float d0 = 0.f, d1 = 0.f, d2 = 0.f, d3 = 0.f;
#pragma unroll
      for (int q = 0; q < 8; ++q) {
        v[q] = xj[q];
        float ax = xi[q].x - v[q].x; d0 = fmaf(ax, ax, d0);
        float ay = xi[q].y - v[q].y; d1 = fmaf(ay, ay, d1);
        float az = xi[q].z - v[q].z; d2 = fmaf(az, az, d2);
        float aw = xi[q].w - v[q].w; d3 = fmaf(aw, aw, d3);
      }
      float k = __expf(-((d0 + d1) + (d2 + d3)) * inv2);
      S += k;
#pragma unroll
      for (int q = 0; q < 8; ++q) {
        acc[q].x = fmaf(k, v[q].x, acc[q].x);
        acc[q].y = fmaf(k, v[q].y, acc[q].y);
        acc[q].z = fmaf(k, v[q].z, acc[q].z);
        acc[q].w = fmaf(k, v[q].w, acc[q].w);
      }
    }
  }
  const float inv = 1.f / ls2;
  const float c1 = inv * S;
  const float c2 = 1.f + inv;
  float4* o = reinterpret_cast<float4*>(out + (size_t)row * DIM);
#pragma unroll
  for (int q = 0; q < 8; ++q) {
    float4 r;
    r.x = (c1 * xi[q].x - c2 * acc[q].x) * (1.f / NPART);
    r.y = (c1 * xi[q].y - c2 * acc[q].y) * (1.f / NPART);
    r.z = (c1 * xi[q].z - c2 * acc[q].z) * (1.f / NPART);
    r.w = (c1 * xi[q].w - c2 * acc[q].w) * (1.f / NPART);
    o[q] = r;
  }
}

// ---------------------------------------------------------------------------
extern "C" void kernel_launch(void* const* d_in, const int* in_sizes, int n_in,
                              void* d_out, int out_size, void* d_ws, size_t ws_size,
                              hipStream_t stream) {
  const float* X = (const float*)d_in[0];
  const float* ls = (const float*)d_in[1];
  float* out = (float*)d_out;
  (void)d_ws;
  (void)ws_size;

  hipError_t e =
      hipMemsetAsync(d_out, 0, (size_t)out_size * sizeof(float), stream);
  if (e == hipSuccess) {
    dim3 grid(NPART / 32, 8);
    svgd_onepass_kernel<<<grid, 256, 0, stream>>>(X, ls, out);
    return;
  }
  svgd_direct_kernel<<<NPART / 256, 256, 0, stream>>>(X, ls, out);
}